// Round 5
// baseline (355.801 us; speedup 1.0000x reference)
//
#include <hip/hip_runtime.h>
#include <stdint.h>
#include <cmath>

// Problem constants
#define B_    2
#define N_    2048
#define DIM_  1536
#define H_    8
#define NPOS  (2*N_ - 1)   // 4095 (posb padded to 4096 rows; pad row never gathered)
#define NB_   32           // basis per class (192/6)

typedef __attribute__((ext_vector_type(8))) short short8;
typedef __attribute__((ext_vector_type(4))) float float4v;

__device__ __forceinline__ float bf2f(unsigned short u) {
    return __uint_as_float(((unsigned int)u) << 16);
}
__device__ __forceinline__ unsigned short f2bf(float f) {
    unsigned int u = __float_as_uint(f);
    u += 0x7FFFu + ((u >> 16) & 1u);   // RNE
    return (unsigned short)(u >> 16);
}
__device__ __forceinline__ unsigned int pack2bf(float lo, float hi) {
    return (unsigned int)f2bf(lo) | ((unsigned int)f2bf(hi) << 16);
}
__device__ __forceinline__ float ldf(const void* p, int isF32, size_t idx) {
    return isF32 ? ((const float*)p)[idx] : bf2f(((const unsigned short*)p)[idx]);
}
// async global->LDS, 16B per lane; LDS dest = base + lane*16 (wave-uniform base!)
__device__ __forceinline__ void gll16(const unsigned short* g, unsigned short* l) {
    __builtin_amdgcn_global_load_lds(
        (const __attribute__((address_space(1))) unsigned int*)g,
        (__attribute__((address_space(3))) unsigned int*)l, 16, 0, 0);
}

// ---------------------------------------------------------------------------
// Workspace layout (bytes). Opart/lpart live in the XB-tail + WT hole, which
// is dead by the time attn runs. Total footprint 35.7 MB (same as round 4).
// ---------------------------------------------------------------------------
constexpr size_t OFF_FLAG = 0;                                   // uint
constexpr size_t OFF_POS  = 256;                                 // bf16 [8][4096][64]
constexpr size_t OFF_Q    = OFF_POS + (size_t)H_*4096*64*2;
constexpr size_t OFF_K    = OFF_Q   + (size_t)B_*H_*N_*64*2;
constexpr size_t OFF_V    = OFF_K   + (size_t)B_*H_*N_*64*2;
constexpr size_t OFF_WOT  = OFF_V   + (size_t)B_*H_*N_*64*2;     // bf16 [1536][512]
constexpr size_t OFF_XB   = OFF_WOT + (size_t)DIM_*512*2;        // bf16 [4096][1536]
constexpr size_t OFF_AO   = OFF_XB;                              // bf16 [4096][512] (alias head of XB)
constexpr size_t OFF_OP   = OFF_AO + (size_t)4096*512*2;         // bf16 [3][16][32][64][64]
constexpr size_t OFF_LP   = OFF_OP + (size_t)3*16*32*4096*2;     // f32  [3][16][32][64]
constexpr size_t OFF_WT   = OFF_XB + (size_t)4096*DIM_*2;        // bf16 [3][512][1536]
// static_assert: OP/LP end (35,520,768) <= WT end (35,651,840): inside old footprint
static_assert(OFF_LP + (size_t)3*16*32*64*4 <= OFF_WT + (size_t)3*512*DIM_*2, "ws overflow");

// ---------------------------------------------------------------------------
// 0) Detect input dtype (bf16 vs fp32) — robustness, ~2 us.
// ---------------------------------------------------------------------------
__global__ __launch_bounds__(256) void detect_kernel(const unsigned short* __restrict__ x,
                                                     unsigned int* __restrict__ flags) {
    __shared__ int cnt[256];
    unsigned short u = x[2 * threadIdx.x];
    int e  = (u >> 7) & 0xFF;
    int ok = (u == 0) || (e >= 95 && e <= 140);
    cnt[threadIdx.x] = ok;
    __syncthreads();
    for (int s = 128; s > 0; s >>= 1) {
        if (threadIdx.x < s) cnt[threadIdx.x] += cnt[threadIdx.x + s];
        __syncthreads();
    }
    if (threadIdx.x == 0) flags[0] = (cnt[0] >= 192) ? 0u : 1u;  // 0=bf16, 1=fp32
}

// ---------------------------------------------------------------------------
// 1) x -> bf16 contiguous (GEMM A-operand)
// ---------------------------------------------------------------------------
__global__ __launch_bounds__(256) void cvtx_kernel(const unsigned int* __restrict__ flags,
                                                   const void* __restrict__ x,
                                                   unsigned short* __restrict__ Xb) {
    const int f32 = (int)flags[0];
    const size_t total = (size_t)4096 * DIM_;
    size_t i = ((size_t)blockIdx.x * 256 + threadIdx.x) * 8;
    const size_t stride = (size_t)gridDim.x * 256 * 8;
    if (f32) {
        for (; i < total; i += stride) {
            float4v a = *reinterpret_cast<const float4v*>((const float*)x + i);
            float4v b = *reinterpret_cast<const float4v*>((const float*)x + i + 4);
            uint4 o;
            o.x = pack2bf(a[0], a[1]); o.y = pack2bf(a[2], a[3]);
            o.z = pack2bf(b[0], b[1]); o.w = pack2bf(b[2], b[3]);
            *reinterpret_cast<uint4*>(Xb + i) = o;
        }
    } else {
        for (; i < total; i += stride)
            *reinterpret_cast<uint4*>(Xb + i) =
                *reinterpret_cast<const uint4*>((const unsigned short*)x + i);
    }
}

// ---------------------------------------------------------------------------
// 2) Weight transposes -> bf16 [N][K]. z<3: Wq/Wk/Wv [1536][512] -> Wt[z][512][1536]
//    z=3: Wo [512][1536] -> Wot[1536][512]. grid (16,48,4) fully utilized.
// ---------------------------------------------------------------------------
__global__ __launch_bounds__(256) void cvtw_kernel(const unsigned int* __restrict__ flags,
                                                   const void* __restrict__ Wq, const void* __restrict__ Wk,
                                                   const void* __restrict__ Wv, const void* __restrict__ Wo,
                                                   unsigned short* __restrict__ Wt,
                                                   unsigned short* __restrict__ Wot) {
    __shared__ unsigned short tile[32][33];
    const int f32 = (int)flags[0];
    const int z = blockIdx.z;
    const void* src = z == 0 ? Wq : (z == 1 ? Wk : (z == 2 ? Wv : Wo));
    unsigned short* dst = (z < 3) ? (Wt + (size_t)z * 512 * DIM_) : Wot;
    const int R = (z < 3) ? DIM_ : 512;
    const int C = (z < 3) ? 512 : DIM_;
    const int x0 = ((z < 3) ? blockIdx.x : blockIdx.y) * 32;
    const int y0 = ((z < 3) ? blockIdx.y : blockIdx.x) * 32;
    const int tx = threadIdx.x & 31, ty = threadIdx.x >> 5;   // ty 0..7
#pragma unroll
    for (int i = 0; i < 4; ++i)
        tile[ty + i * 8][tx] = f2bf(ldf(src, f32, (size_t)(y0 + ty + i * 8) * C + x0 + tx));
    __syncthreads();
#pragma unroll
    for (int i = 0; i < 4; ++i)
        dst[(size_t)(x0 + ty + i * 8) * R + y0 + tx] = tile[tx][ty + i * 8];
}

// ---------------------------------------------------------------------------
// 3) Fused positional basis + projection: posb[h][j][d] = (emb @ Wrel), bf16.
// ---------------------------------------------------------------------------
__global__ __launch_bounds__(512) void posproj_kernel(double maxp,
                                                      const void* __restrict__ Wrel,
                                                      const unsigned int* __restrict__ flags,
                                                      unsigned short* __restrict__ posb) {
    __shared__ float eb[8 * 192];
    const int f32 = (int)flags[0];
    const int j0  = blockIdx.x * 8;
    const int c   = threadIdx.x;   // 0..511
    const double max_range = log((double)N_) / log(2.0);   // 11.0

    for (int u = c; u < 8 * 96; u += 512) {
        int rr = u / 96, f = u - rr * 96;
        int j = j0 + rr;
        float v = 0.f, sg = 0.f;
        if (j < NPOS) {
            int dd  = j - (N_ - 1);
            int adI = dd < 0 ? -dd : dd;
            double ad = (double)adI;
            double val;
            if (f < 32) {
                double t = 3.0 + (double)f * (max_range - 3.0) / 31.0;
                val = exp2(-ad / exp2(t));
            } else if (f < 64) {
                double width = exp2((double)(f - 31)) - 1.0;
                val = (width > ad) ? 1.0 : 0.0;
            } else {
                int g = f - 64;
                double mean = 64.0 * (g + 1);
                double conc = (mean / 32.0) * (mean / 32.0);
                double rate = mean / 1024.0;
                double pp = (adI == 0) ? 1e-8
                          : exp((conc - 1.0) * log(ad) - rate * ad - lgamma(conc) + conc * log(rate)) + 1e-8;
                val = pp / maxp;
            }
            v  = (float)val;
            sg = (dd > 0) ? 1.f : ((dd < 0) ? -1.f : 0.f);
        }
        eb[rr * 192 + f]      = v;
        eb[rr * 192 + 96 + f] = sg * v;
    }
    __syncthreads();

    float acc[8] = {0, 0, 0, 0, 0, 0, 0, 0};
    for (int k = 0; k < 192; ++k) {
        float w = ldf(Wrel, f32, (size_t)k * 512 + c);
#pragma unroll
        for (int rr = 0; rr < 8; ++rr) acc[rr] += eb[rr * 192 + k] * w;
    }
    int h = c >> 6, dcol = c & 63;
    for (int rr = 0; rr < 8; ++rr) {
        int j = j0 + rr;
        if (j < NPOS)
            posb[((size_t)h * 4096 + j) * 64 + dcol] = f2bf(acc[rr]);
    }
}

// ---------------------------------------------------------------------------
// m97-style 128x128 GEMM core: A [M][K] bf16 row-major, Bt [N][K] bf16 row-major.
// ---------------------------------------------------------------------------
__device__ __forceinline__ void gemm128_core(const unsigned short* __restrict__ A,
                                             const unsigned short* __restrict__ Bt,
                                             int K, int row0, int col0,
                                             unsigned short* As, unsigned short* Bs,
                                             float4v acc[4][4]) {
    const int tid = threadIdx.x, lane = tid & 63, w = tid >> 6;
    const int l15 = lane & 15, q8 = (lane >> 4) * 8;
    const int wr = (w & 1) * 64, wc = (w >> 1) * 64;
    const int sr = lane >> 2, sc8 = (lane & 3) * 8;
    const int ch0 = 2 * w, ch1 = 2 * w + 1;
    for (int k0 = 0; k0 < K; k0 += 32) {
        __syncthreads();
        gll16(&A [(size_t)(row0 + ch0 * 16 + sr) * K + k0 + sc8], &As[ch0 * 512]);
        gll16(&A [(size_t)(row0 + ch1 * 16 + sr) * K + k0 + sc8], &As[ch1 * 512]);
        gll16(&Bt[(size_t)(col0 + ch0 * 16 + sr) * K + k0 + sc8], &Bs[ch0 * 512]);
        gll16(&Bt[(size_t)(col0 + ch1 * 16 + sr) * K + k0 + sc8], &Bs[ch1 * 512]);
        __syncthreads();
        short8 a[4], b[4];
#pragma unroll
        for (int mi = 0; mi < 4; ++mi)
            a[mi] = *reinterpret_cast<const short8*>(&As[(wr + mi * 16 + l15) * 32 + q8]);
#pragma unroll
        for (int ni = 0; ni < 4; ++ni)
            b[ni] = *reinterpret_cast<const short8*>(&Bs[(wc + ni * 16 + l15) * 32 + q8]);
#pragma unroll
        for (int mi = 0; mi < 4; ++mi)
#pragma unroll
            for (int ni = 0; ni < 4; ++ni)
                acc[mi][ni] = __builtin_amdgcn_mfma_f32_16x16x32_bf16(a[mi], b[ni], acc[mi][ni], 0, 0, 0);
    }
}

// ---------------------------------------------------------------------------
// 4) QKV single dispatch: Wt is [1536 n][1536 k]; mode = n>>9. grid (12,32).
// ---------------------------------------------------------------------------
__global__ __launch_bounds__(256) void qkv_kernel(const unsigned short* __restrict__ Xb,
                                                  const unsigned short* __restrict__ Wt,
                                                  unsigned short* __restrict__ qbuf,
                                                  unsigned short* __restrict__ kbuf,
                                                  unsigned short* __restrict__ vbuf) {
    __shared__ __align__(16) unsigned short As[128 * 32];
    __shared__ __align__(16) unsigned short Bs[128 * 32];
    const int row0 = blockIdx.y * 128, col0 = blockIdx.x * 128;
    float4v acc[4][4];
#pragma unroll
    for (int mi = 0; mi < 4; ++mi)
#pragma unroll
        for (int ni = 0; ni < 4; ++ni) acc[mi][ni] = (float4v){0.f, 0.f, 0.f, 0.f};
    gemm128_core(Xb, Wt, DIM_, row0, col0, As, Bs, acc);
    const int lane = threadIdx.x & 63, w = threadIdx.x >> 6;
    const int l15 = lane & 15, quad = lane >> 4;
    const int wr = (w & 1) * 64, wc = (w >> 1) * 64;
#pragma unroll
    for (int mi = 0; mi < 4; ++mi)
#pragma unroll
        for (int ni = 0; ni < 4; ++ni) {
            int n = col0 + wc + ni * 16 + l15;
            int mode = n >> 9, nn = n & 511;
            int hh = nn >> 6, dd = nn & 63;
            unsigned short* Obuf = mode == 0 ? qbuf : (mode == 1 ? kbuf : vbuf);
            float scale = (mode == 0) ? 0.125f : 1.0f;
#pragma unroll
            for (int r = 0; r < 4; ++r) {
                int m = row0 + wr + mi * 16 + quad * 4 + r;
                int bb = m >> 11, ii = m & 2047;
                Obuf[((size_t)(bb * 8 + hh) * N_ + ii) * 64 + dd] = f2bf(acc[mi][ni][r] * scale);
            }
        }
}

// ---------------------------------------------------------------------------
// 5) MFMA flash attention, j-split across 3 blocks (O,l are pure sums over j).
//    S = (q+rcb)·k_j + (q+rpb)·pos_t, t=j-i+2047; P=exp(S) (no max: |S|<~30,
//    fp32-safe). K/pos b-frags in REGISTERS, prefetched at tile start.
//    LDS: Vt + Pp + Rb = 35.3 KB. Partials: O (bf16, unnormalized) + l (f32).
// ---------------------------------------------------------------------------
#define VLD 72    // Vt/Pp row stride (144B, 16B-aligned)
#define RST 66    // Rb [col][m] stride (132B: 8B-aligned, bank-spread)

__global__ __launch_bounds__(256) void attn_kernel(const unsigned int* __restrict__ flags,
                                                   const unsigned short* __restrict__ qb,
                                                   const unsigned short* __restrict__ kb,
                                                   const unsigned short* __restrict__ vb,
                                                   const unsigned short* __restrict__ posb,
                                                   const void* __restrict__ rcb,
                                                   const void* __restrict__ rpb,
                                                   unsigned short* __restrict__ Opart,
                                                   float* __restrict__ lpart) {
    __shared__ __align__(16) unsigned short Vt[64 * VLD];    // [d][j]
    __shared__ __align__(16) unsigned short Pp[64 * VLD];    // [i][j] (wave-private rows)
    __shared__ __align__(8)  unsigned short Rb[128 * RST];   // rel ring [tcol][m] (wave-private m)

    const int f32 = (int)flags[0];
    const int tid = threadIdx.x;
    const int it = blockIdx.x, bh = blockIdx.y, z = blockIdx.z;
    const int h = bh & 7;
    const int i0 = it * 64;
    const size_t qoff = (size_t)bh * N_ * 64;
    const size_t poff = (size_t)h * 4096 * 64;
    const int lane = tid & 63, w = tid >> 6;
    const int l15 = lane & 15, quad = lane >> 4, q8 = quad * 8;
    const int m0 = w * 16 + quad * 4;

    // ---- Q fragments (contiguous 16B in global), biases folded ----
    short8 afc[2], afr[2];
#pragma unroll
    for (int kc = 0; kc < 2; ++kc) {
        uint4 qv = *reinterpret_cast<const uint4*>(
            &qb[qoff + (size_t)(i0 + w * 16 + l15) * 64 + kc * 32 + q8]);
        unsigned int uu[4] = {qv.x, qv.y, qv.z, qv.w};
        unsigned int cw[4], rw[4];
#pragma unroll
        for (int e = 0; e < 4; ++e) {
            int k = h * 64 + kc * 32 + q8 + 2 * e;
            float lo = __uint_as_float(uu[e] << 16);
            float hi = __uint_as_float(uu[e] & 0xffff0000u);
            cw[e] = pack2bf(lo + ldf(rcb, f32, k), hi + ldf(rcb, f32, k + 1));
            rw[e] = pack2bf(lo + ldf(rpb, f32, k), hi + ldf(rpb, f32, k + 1));
        }
        union { uint4 u; short8 s; } cv, rv2;
        cv.u  = (uint4){cw[0], cw[1], cw[2], cw[3]};
        rv2.u = (uint4){rw[0], rw[1], rw[2], rw[3]};
        afc[kc] = cv.s;
        afr[kc] = rv2.s;
    }

    float4v Oa[4];
#pragma unroll
    for (int nb = 0; nb < 4; ++nb) Oa[nb] = (float4v){0.f, 0.f, 0.f, 0.f};
    float lsum[4] = {0.f, 0.f, 0.f, 0.f};

    const int base0 = 1984 - i0;
    const int t0 = z * 11, t1 = (z == 2) ? 32 : (t0 + 11);   // tile range for this split

    // ---- seed ring: cols [base0+t0*64, +63] ----
    {
        const int cs = base0 + t0 * 64;
        float4v R[4];
#pragma unroll
        for (int nb = 0; nb < 4; ++nb) R[nb] = (float4v){0.f, 0.f, 0.f, 0.f};
#pragma unroll
        for (int kc = 0; kc < 2; ++kc)
#pragma unroll
            for (int nb = 0; nb < 4; ++nb) {
                short8 pb = *reinterpret_cast<const short8*>(
                    &posb[poff + (size_t)(cs + nb * 16 + l15) * 64 + kc * 32 + q8]);
                R[nb] = __builtin_amdgcn_mfma_f32_16x16x32_bf16(afr[kc], pb, R[nb], 0, 0, 0);
            }
        const int cb0 = cs & 127;
#pragma unroll
        for (int nb = 0; nb < 4; ++nb) {
            union { unsigned short us[4]; uint2 u2; } rv;
#pragma unroll
            for (int r = 0; r < 4; ++r) rv.us[r] = f2bf(R[nb][r]);
            *reinterpret_cast<uint2*>(&Rb[(size_t)(cb0 + nb * 16 + l15) * RST + m0]) = rv.u2;
        }
    }

    for (int jt = t0; jt < t1; ++jt) {
        const int j0 = jt * 64, basej = base0 + j0;
        __syncthreads();   // prior PV done reading Vt

        // ---- prefetch K frags + pos frags into registers (consumed later) ----
        short8 kf[2][4], pf8[2][4];
        {
            const int cs = basej + 64;
#pragma unroll
            for (int kc = 0; kc < 2; ++kc)
#pragma unroll
                for (int nb = 0; nb < 4; ++nb) {
                    kf[kc][nb] = *reinterpret_cast<const short8*>(
                        &kb[qoff + (size_t)(j0 + nb * 16 + l15) * 64 + kc * 32 + q8]);
                    pf8[kc][nb] = *reinterpret_cast<const short8*>(
                        &posb[poff + (size_t)(cs + nb * 16 + l15) * 64 + kc * 32 + q8]);
                }
        }

        // ---- stage V transposed: Vt[d][j] ----
        {
            int jj = (tid & 31) * 2, dv = (tid >> 5) * 8;
            uint4 r0 = *reinterpret_cast<const uint4*>(&vb[qoff + (size_t)(j0 + jj) * 64 + dv]);
            uint4 r1 = *reinterpret_cast<const uint4*>(&vb[qoff + (size_t)(j0 + jj + 1) * 64 + dv]);
            const unsigned short* p0 = (const unsigned short*)&r0;
            const unsigned short* p1 = (const unsigned short*)&r1;
#pragma unroll
            for (int e = 0; e < 8; ++e) {
                unsigned int pk = (unsigned int)p0[e] | ((unsigned int)p1[e] << 16);
                *reinterpret_cast<unsigned int*>(&Vt[(dv + e) * VLD + jj]) = pk;
            }
        }

        // ---- rel GEMM -> 64 new ring cols at basej+64 ----
        {
            float4v R[4];
#pragma unroll
            for (int nb = 0; nb < 4; ++nb) R[nb] = (float4v){0.f, 0.f, 0.f, 0.f};
#pragma unroll
            for (int kc = 0; kc < 2; ++kc)
#pragma unroll
                for (int nb = 0; nb < 4; ++nb)
                    R[nb] = __builtin_amdgcn_mfma_f32_16x16x32_bf16(afr[kc], pf8[kc][nb], R[nb], 0, 0, 0);
            const int cb0 = (basej + 64) & 127;
#pragma unroll
            for (int nb = 0; nb < 4; ++nb) {
                union { unsigned short us[4]; uint2 u2; } rv;
#pragma unroll
                for (int r = 0; r < 4; ++r) rv.us[r] = f2bf(R[nb][r]);
                *reinterpret_cast<uint2*>(&Rb[(size_t)(cb0 + nb * 16 + l15) * RST + m0]) = rv.u2;
            }
        }

        // ---- content GEMM: Sacc = Qc · K^T ----
        float4v Sacc[4];
#pragma unroll
        for (int nb = 0; nb < 4; ++nb) Sacc[nb] = (float4v){0.f, 0.f, 0.f, 0.f};
#pragma unroll
        for (int kc = 0; kc < 2; ++kc)
#pragma unroll
            for (int nb = 0; nb < 4; ++nb)
                Sacc[nb] = __builtin_amdgcn_mfma_f32_16x16x32_bf16(afc[kc], kf[kc][nb], Sacc[nb], 0, 0, 0);

        // ---- gather rel diagonal, P = exp(S), lane row-sums, stash P ----
#pragma unroll
        for (int nb = 0; nb < 4; ++nb) {
            const int jl = nb * 16 + l15;
#pragma unroll
            for (int r = 0; r < 4; ++r) {
                int t = basej + 63 + jl - (m0 + r);
                float s = Sacc[nb][r] + bf2f(Rb[(size_t)(t & 127) * RST + m0 + r]);
                float p = __expf(s);
                lsum[r] += p;
                Pp[(m0 + r) * VLD + jl] = f2bf(p);
            }
        }
        __syncthreads();   // Vt writes visible to all waves before PV

        // ---- PV GEMM: Oa += P · V ----
#pragma unroll
        for (int kc = 0; kc < 2; ++kc) {
            short8 pf = *reinterpret_cast<const short8*>(&Pp[(w * 16 + l15) * VLD + kc * 32 + q8]);
#pragma unroll
            for (int nb = 0; nb < 4; ++nb) {
                short8 vf = *reinterpret_cast<const short8*>(&Vt[(nb * 16 + l15) * VLD + kc * 32 + q8]);
                Oa[nb] = __builtin_amdgcn_mfma_f32_16x16x32_bf16(pf, vf, Oa[nb], 0, 0, 0);
            }
        }
    }

    // ---- reduce row sums, write partials ----
#pragma unroll
    for (int r = 0; r < 4; ++r)
#pragma unroll
        for (int off = 1; off < 16; off <<= 1) lsum[r] += __shfl_xor(lsum[r], off);
    const size_t pslot = (size_t)(z * 16 + bh) * 32 + it;
    const size_t obase = pslot * 4096;
#pragma unroll
    for (int nb = 0; nb < 4; ++nb)
#pragma unroll
        for (int r = 0; r < 4; ++r)
            Opart[obase + (size_t)(m0 + r) * 64 + nb * 16 + l15] = f2bf(Oa[nb][r]);
    if (l15 == 0) {
#pragma unroll
        for (int r = 0; r < 4; ++r) lpart[pslot * 64 + m0 + r] = lsum[r];
    }
}

// ---------------------------------------------------------------------------
// 6) Combine j-split partials, normalize, write ao[b][i][h*64+d] bf16.
// ---------------------------------------------------------------------------
__global__ __launch_bounds__(256) void combine_kernel(const unsigned short* __restrict__ Opart,
                                                      const float* __restrict__ lpart,
                                                      unsigned short* __restrict__ ao) {
    const int it = blockIdx.x, bh = blockIdx.y;
    const int h = bh & 7, b = bh >> 3, i0 = it * 64;
    const int tid = threadIdx.x;
    const int row = tid >> 2, c0 = (tid & 3) * 16;
    float o[16];
#pragma unroll
    for (int e = 0; e < 16; ++e) o[e] = 0.f;
    float l = 0.f;
#pragma unroll
    for (int z = 0; z < 3; ++z) {
        const size_t pslot = (size_t)(z * 16 + bh) * 32 + it;
        const size_t ob = pslot * 4096 + (size_t)row * 64 + c0;
        uint4 a = *reinterpret_cast<const uint4*>(&Opart[ob]);
        uint4 b4 = *reinterpret_cast<const uint4*>(&Opart[ob + 8]);
        unsigned int uu[8] = {a.x, a.y, a.z, a.w, b4.x, b4.y, b4.z, b4.w};
#pragma unroll
        for (int e = 0; e < 8; ++e) {
            o[2 * e]     += __uint_as_float(uu[e] << 16);
            o[2 * e + 1] += __uint_as_float(uu[e] & 0xffff0000u);
        }
        l += lpart[pslot * 64 + row];
    }
    float inv = 1.0f / l;
    unsigned int ou[8];
#pragma unroll
    for (int e = 0; e < 8; ++e) ou[e] = pack2bf(o[2 * e] * inv, o[2 * e + 1] * inv);
    unsigned short* dst = &ao[((size_t)b * N_ + i0 + row) * 512 + h * 64 + c0];
    *reinterpret_cast<uint4*>(dst)     = (uint4){ou[0], ou[1], ou[2], ou[3]};
    *reinterpret_cast<uint4*>(dst + 8) = (uint4){ou[4], ou[5], ou[6], ou[7]};
}

// ---------------------------------------------------------------------------
// 7) out = ao @ Wo + bo (output dtype per flag). grid (12, 32).
// ---------------------------------------------------------------------------
__global__ __launch_bounds__(256) void outproj_kernel(const unsigned int* __restrict__ flags,
                                                      const unsigned short* __restrict__ AO,
                                                      const unsigned short* __restrict__ Wot,
                                                      const void* __restrict__ bo,
                                                      void* __restrict__ out) {
    __shared__ __align__(16) unsigned short As[128 * 32];
    __shared__ __align__(16) unsigned short Bs[128 * 32];
    const int f32 = (int)flags[0];
    const int row0 = blockIdx.y * 128, col0 = blockIdx.x * 128;
    float4v acc[4][4];
#pragma unroll
    for (int mi = 0; mi < 4; ++mi)
#pragma unroll
        for (int ni = 0; ni < 4; ++ni) acc[mi][ni] = (float4v){0.f, 0.f, 0.f, 0.f};
    gemm128_core(AO, Wot, 512, row0, col0, As, Bs, acc);
    const int lane = threadIdx.x & 63, w = threadIdx.x >> 6;
    const int l15 = lane & 15, quad = lane >> 4;
    const int wr = (w & 1) * 64, wc = (w >> 1) * 64;
#pragma unroll
    for (int mi = 0; mi < 4; ++mi)
#pragma unroll
        for (int ni = 0; ni < 4; ++ni) {
            int n = col0 + wc + ni * 16 + l15;
            float bias = ldf(bo, f32, n);
#pragma unroll
            for (int r = 0; r < 4; ++r) {
                int m = row0 + wr + mi * 16 + quad * 4 + r;
                float v = acc[mi][ni][r] + bias;
                if (f32) ((float*)out)[(size_t)m * DIM_ + n] = v;
                else     ((unsigned short*)out)[(size_t)m * DIM_ + n] = f2bf(v);
            }
        }
}

// ---------------------------------------------------------------------------
extern "C" void kernel_launch(void* const* d_in, const int* in_sizes, int n_in,
                              void* d_out, int out_size, void* d_ws, size_t ws_size,
                              hipStream_t stream) {
    const void* x    = d_in[0];
    const void* Wq   = d_in[1];
    const void* Wk   = d_in[2];
    const void* Wv   = d_in[3];
    const void* Wo   = d_in[4];
    const void* bo   = d_in[5];
    const void* Wrel = d_in[6];
    const void* rcb  = d_in[7];
    const void* rpb  = d_in[8];

    char* ws = (char*)d_ws;
    unsigned int*   flags = (unsigned int*)(ws + OFF_FLAG);
    unsigned short* posb  = (unsigned short*)(ws + OFF_POS);
    unsigned short* qbuf  = (unsigned short*)(ws + OFF_Q);
    unsigned short* kbuf  = (unsigned short*)(ws + OFF_K);
    unsigned short* vbuf  = (unsigned short*)(ws + OFF_V);
    unsigned short* Wot   = (unsigned short*)(ws + OFF_WOT);
    unsigned short* Xb    = (unsigned short*)(ws + OFF_XB);
    unsigned short* ao    = (unsigned short*)(ws + OFF_AO);   // aliases XB head (dead after qkv)
    unsigned short* Opart = (unsigned short*)(ws + OFF_OP);   // XB tail + WT hole (dead after qkv)
    float*          lpart = (float*)(ws + OFF_LP);
    unsigned short* Wt    = (unsigned short*)(ws + OFF_WT);

    // maxp: pure function of compile-time constants; host-side (capture-time only)
    double maxp = 0.0;
    for (int g = 0; g < NB_; ++g) {
        double mean = 64.0 * (g + 1);
        double conc = (mean / 32.0) * (mean / 32.0);
        double rate = mean / 1024.0;
        double lgc  = std::lgamma(conc);
        double clr  = conc * std::log(rate);
        for (int ad = 1; ad < N_; ++ad) {
            double lp = (conc - 1.0) * std::log((double)ad) - rate * (double)ad - lgc + clr;
            double p  = std::exp(lp) + 1e-8;
            if (p > maxp) maxp = p;
        }
    }

    detect_kernel<<<dim3(1), dim3(256), 0, stream>>>((const unsigned short*)x, flags);
    cvtx_kernel<<<dim3(1024), dim3(256), 0, stream>>>(flags, x, Xb);
    cvtw_kernel<<<dim3(16, 48, 4), dim3(256), 0, stream>>>(flags, Wq, Wk, Wv, Wo, Wt, Wot);
    posproj_kernel<<<dim3(512), dim3(512), 0, stream>>>(maxp, Wrel, flags, posb);
    qkv_kernel<<<dim3(12, 32), dim3(256), 0, stream>>>(Xb, Wt, qbuf, kbuf, vbuf);
    attn_kernel<<<dim3(32, 16, 3), dim3(256), 0, stream>>>(flags, qbuf, kbuf, vbuf, posb, rcb, rpb, Opart, lpart);
    combine_kernel<<<dim3(32, 16), dim3(256), 0, stream>>>(Opart, lpart, ao);
    outproj_kernel<<<dim3(12, 32), dim3(256), 0, stream>>>(flags, ao, Wot, bo, d_out);
}

// Round 6
// 292.433 us; speedup vs baseline: 1.2167x; 1.2167x over previous
//
#include <hip/hip_runtime.h>
#include <stdint.h>
#include <cmath>

// Problem constants
#define B_    2
#define N_    2048
#define DIM_  1536
#define H_    8
#define NPOS  (2*N_ - 1)   // 4095 (posb padded to 4096 rows; pad row never gathered)
#define NB_   32           // basis per class (192/6)

typedef __attribute__((ext_vector_type(8))) short short8;
typedef __attribute__((ext_vector_type(4))) float float4v;

__device__ __forceinline__ float bf2f(unsigned short u) {
    return __uint_as_float(((unsigned int)u) << 16);
}
__device__ __forceinline__ unsigned short f2bf(float f) {
    unsigned int u = __float_as_uint(f);
    u += 0x7FFFu + ((u >> 16) & 1u);   // RNE
    return (unsigned short)(u >> 16);
}
__device__ __forceinline__ unsigned int pack2bf(float lo, float hi) {
    return (unsigned int)f2bf(lo) | ((unsigned int)f2bf(hi) << 16);
}
__device__ __forceinline__ float ldf(const void* p, int isF32, size_t idx) {
    return isF32 ? ((const float*)p)[idx] : bf2f(((const unsigned short*)p)[idx]);
}
// async global->LDS, 16B per lane; LDS dest = base + lane*16 (wave-uniform base!)
__device__ __forceinline__ void gll16(const unsigned short* g, unsigned short* l) {
    __builtin_amdgcn_global_load_lds(
        (const __attribute__((address_space(1))) unsigned int*)g,
        (__attribute__((address_space(3))) unsigned int*)l, 16, 0, 0);
}

// ---------------------------------------------------------------------------
// Workspace layout (bytes) — unchanged from round 5 (35.7 MB).
// ---------------------------------------------------------------------------
constexpr size_t OFF_FLAG = 0;                                   // uint
constexpr size_t OFF_POS  = 256;                                 // bf16 [8][4096][64]
constexpr size_t OFF_Q    = OFF_POS + (size_t)H_*4096*64*2;
constexpr size_t OFF_K    = OFF_Q   + (size_t)B_*H_*N_*64*2;
constexpr size_t OFF_V    = OFF_K   + (size_t)B_*H_*N_*64*2;
constexpr size_t OFF_WOT  = OFF_V   + (size_t)B_*H_*N_*64*2;     // bf16 [1536][512]
constexpr size_t OFF_XB   = OFF_WOT + (size_t)DIM_*512*2;        // bf16 [4096][1536]
constexpr size_t OFF_AO   = OFF_XB;                              // bf16 [4096][512] (alias head of XB)
constexpr size_t OFF_OP   = OFF_AO + (size_t)4096*512*2;         // bf16 [3][16][32][64][64]
constexpr size_t OFF_LP   = OFF_OP + (size_t)3*16*32*4096*2;     // f32  [3][16][32][64]
constexpr size_t OFF_WT   = OFF_XB + (size_t)4096*DIM_*2;        // bf16 [3][512][1536]
static_assert(OFF_LP + (size_t)3*16*32*64*4 <= OFF_WT + (size_t)3*512*DIM_*2, "ws overflow");

// ---------------------------------------------------------------------------
// 0) Detect input dtype (bf16 vs fp32) — robustness, ~2 us.
// ---------------------------------------------------------------------------
__global__ __launch_bounds__(256) void detect_kernel(const unsigned short* __restrict__ x,
                                                     unsigned int* __restrict__ flags) {
    __shared__ int cnt[256];
    unsigned short u = x[2 * threadIdx.x];
    int e  = (u >> 7) & 0xFF;
    int ok = (u == 0) || (e >= 95 && e <= 140);
    cnt[threadIdx.x] = ok;
    __syncthreads();
    for (int s = 128; s > 0; s >>= 1) {
        if (threadIdx.x < s) cnt[threadIdx.x] += cnt[threadIdx.x + s];
        __syncthreads();
    }
    if (threadIdx.x == 0) flags[0] = (cnt[0] >= 192) ? 0u : 1u;  // 0=bf16, 1=fp32
}

// ---------------------------------------------------------------------------
// 1) x -> bf16 contiguous (GEMM A-operand)
// ---------------------------------------------------------------------------
__global__ __launch_bounds__(256) void cvtx_kernel(const unsigned int* __restrict__ flags,
                                                   const void* __restrict__ x,
                                                   unsigned short* __restrict__ Xb) {
    const int f32 = (int)flags[0];
    const size_t total = (size_t)4096 * DIM_;
    size_t i = ((size_t)blockIdx.x * 256 + threadIdx.x) * 8;
    const size_t stride = (size_t)gridDim.x * 256 * 8;
    if (f32) {
        for (; i < total; i += stride) {
            float4v a = *reinterpret_cast<const float4v*>((const float*)x + i);
            float4v b = *reinterpret_cast<const float4v*>((const float*)x + i + 4);
            uint4 o;
            o.x = pack2bf(a[0], a[1]); o.y = pack2bf(a[2], a[3]);
            o.z = pack2bf(b[0], b[1]); o.w = pack2bf(b[2], b[3]);
            *reinterpret_cast<uint4*>(Xb + i) = o;
        }
    } else {
        for (; i < total; i += stride)
            *reinterpret_cast<uint4*>(Xb + i) =
                *reinterpret_cast<const uint4*>((const unsigned short*)x + i);
    }
}

// ---------------------------------------------------------------------------
// 2) Weight transposes -> bf16 [N][K]. z<3: Wq/Wk/Wv -> Wt[z][512][1536];
//    z=3: Wo -> Wot[1536][512].
// ---------------------------------------------------------------------------
__global__ __launch_bounds__(256) void cvtw_kernel(const unsigned int* __restrict__ flags,
                                                   const void* __restrict__ Wq, const void* __restrict__ Wk,
                                                   const void* __restrict__ Wv, const void* __restrict__ Wo,
                                                   unsigned short* __restrict__ Wt,
                                                   unsigned short* __restrict__ Wot) {
    __shared__ unsigned short tile[32][33];
    const int f32 = (int)flags[0];
    const int z = blockIdx.z;
    const void* src = z == 0 ? Wq : (z == 1 ? Wk : (z == 2 ? Wv : Wo));
    unsigned short* dst = (z < 3) ? (Wt + (size_t)z * 512 * DIM_) : Wot;
    const int R = (z < 3) ? DIM_ : 512;
    const int C = (z < 3) ? 512 : DIM_;
    const int x0 = ((z < 3) ? blockIdx.x : blockIdx.y) * 32;
    const int y0 = ((z < 3) ? blockIdx.y : blockIdx.x) * 32;
    const int tx = threadIdx.x & 31, ty = threadIdx.x >> 5;   // ty 0..7
#pragma unroll
    for (int i = 0; i < 4; ++i)
        tile[ty + i * 8][tx] = f2bf(ldf(src, f32, (size_t)(y0 + ty + i * 8) * C + x0 + tx));
    __syncthreads();
#pragma unroll
    for (int i = 0; i < 4; ++i)
        dst[(size_t)(x0 + ty + i * 8) * R + y0 + tx] = tile[tx][ty + i * 8];
}

// ---------------------------------------------------------------------------
// 3) Fused positional basis + projection: posb[h][j][d] = (emb @ Wrel), bf16.
// ---------------------------------------------------------------------------
__global__ __launch_bounds__(512) void posproj_kernel(double maxp,
                                                      const void* __restrict__ Wrel,
                                                      const unsigned int* __restrict__ flags,
                                                      unsigned short* __restrict__ posb) {
    __shared__ float eb[8 * 192];
    const int f32 = (int)flags[0];
    const int j0  = blockIdx.x * 8;
    const int c   = threadIdx.x;   // 0..511
    const double max_range = log((double)N_) / log(2.0);   // 11.0

    for (int u = c; u < 8 * 96; u += 512) {
        int rr = u / 96, f = u - rr * 96;
        int j = j0 + rr;
        float v = 0.f, sg = 0.f;
        if (j < NPOS) {
            int dd  = j - (N_ - 1);
            int adI = dd < 0 ? -dd : dd;
            double ad = (double)adI;
            double val;
            if (f < 32) {
                double t = 3.0 + (double)f * (max_range - 3.0) / 31.0;
                val = exp2(-ad / exp2(t));
            } else if (f < 64) {
                double width = exp2((double)(f - 31)) - 1.0;
                val = (width > ad) ? 1.0 : 0.0;
            } else {
                int g = f - 64;
                double mean = 64.0 * (g + 1);
                double conc = (mean / 32.0) * (mean / 32.0);
                double rate = mean / 1024.0;
                double pp = (adI == 0) ? 1e-8
                          : exp((conc - 1.0) * log(ad) - rate * ad - lgamma(conc) + conc * log(rate)) + 1e-8;
                val = pp / maxp;
            }
            v  = (float)val;
            sg = (dd > 0) ? 1.f : ((dd < 0) ? -1.f : 0.f);
        }
        eb[rr * 192 + f]      = v;
        eb[rr * 192 + 96 + f] = sg * v;
    }
    __syncthreads();

    float acc[8] = {0, 0, 0, 0, 0, 0, 0, 0};
#pragma unroll 4
    for (int k = 0; k < 192; ++k) {
        float w = ldf(Wrel, f32, (size_t)k * 512 + c);
#pragma unroll
        for (int rr = 0; rr < 8; ++rr) acc[rr] += eb[rr * 192 + k] * w;
    }
    int h = c >> 6, dcol = c & 63;
    for (int rr = 0; rr < 8; ++rr) {
        int j = j0 + rr;
        if (j < NPOS)
            posb[((size_t)h * 4096 + j) * 64 + dcol] = f2bf(acc[rr]);
    }
}

// ---------------------------------------------------------------------------
// 64x128 GEMM core (m97-style staging): A [M][K] bf16 rm, Bt [N][K] bf16 rm.
// BK=32. Wave w: rows (w&1)*32 + mi*16, cols (w>>1)*64 + ni*16. 8 MFMA/iter.
// ---------------------------------------------------------------------------
__device__ __forceinline__ void gemm64x128_core(const unsigned short* __restrict__ A,
                                                const unsigned short* __restrict__ Bt,
                                                int K, int row0, int col0,
                                                unsigned short* As, unsigned short* Bs,
                                                float4v acc[2][4]) {
    const int tid = threadIdx.x, lane = tid & 63, w = tid >> 6;
    const int l15 = lane & 15, q8 = (lane >> 4) * 8;
    const int mr0 = (w & 1) * 32, nc0 = (w >> 1) * 64;
    const int sr = lane >> 2, sc8 = (lane & 3) * 8;
    for (int k0 = 0; k0 < K; k0 += 32) {
        __syncthreads();
        gll16(&A [(size_t)(row0 + w * 16 + sr) * K + k0 + sc8],      &As[w * 512]);
        gll16(&Bt[(size_t)(col0 + w * 32 + sr) * K + k0 + sc8],      &Bs[w * 1024]);
        gll16(&Bt[(size_t)(col0 + w * 32 + 16 + sr) * K + k0 + sc8], &Bs[w * 1024 + 512]);
        __syncthreads();
        short8 a[2], b[4];
#pragma unroll
        for (int mi = 0; mi < 2; ++mi)
            a[mi] = *reinterpret_cast<const short8*>(&As[(mr0 + mi * 16 + l15) * 32 + q8]);
#pragma unroll
        for (int ni = 0; ni < 4; ++ni)
            b[ni] = *reinterpret_cast<const short8*>(&Bs[(nc0 + ni * 16 + l15) * 32 + q8]);
#pragma unroll
        for (int mi = 0; mi < 2; ++mi)
#pragma unroll
            for (int ni = 0; ni < 4; ++ni)
                acc[mi][ni] = __builtin_amdgcn_mfma_f32_16x16x32_bf16(a[mi], b[ni], acc[mi][ni], 0, 0, 0);
    }
}

// ---------------------------------------------------------------------------
// 4) QKV single dispatch: Wt [1536 n][1536 k]; mode = n>>9. grid (12,64).
// ---------------------------------------------------------------------------
__global__ __launch_bounds__(256) void qkv_kernel(const unsigned short* __restrict__ Xb,
                                                  const unsigned short* __restrict__ Wt,
                                                  unsigned short* __restrict__ qbuf,
                                                  unsigned short* __restrict__ kbuf,
                                                  unsigned short* __restrict__ vbuf) {
    __shared__ __align__(16) unsigned short As[64 * 32];
    __shared__ __align__(16) unsigned short Bs[128 * 32];
    const int row0 = blockIdx.y * 64, col0 = blockIdx.x * 128;
    float4v acc[2][4];
#pragma unroll
    for (int mi = 0; mi < 2; ++mi)
#pragma unroll
        for (int ni = 0; ni < 4; ++ni) acc[mi][ni] = (float4v){0.f, 0.f, 0.f, 0.f};
    gemm64x128_core(Xb, Wt, DIM_, row0, col0, As, Bs, acc);
    const int lane = threadIdx.x & 63, w = threadIdx.x >> 6;
    const int l15 = lane & 15, quad = lane >> 4;
    const int mr0 = (w & 1) * 32, nc0 = (w >> 1) * 64;
#pragma unroll
    for (int mi = 0; mi < 2; ++mi)
#pragma unroll
        for (int ni = 0; ni < 4; ++ni) {
            int n = col0 + nc0 + ni * 16 + l15;
            int mode = n >> 9, nn = n & 511;
            int hh = nn >> 6, dd = nn & 63;
            unsigned short* Obuf = mode == 0 ? qbuf : (mode == 1 ? kbuf : vbuf);
            float scale = (mode == 0) ? 0.125f : 1.0f;
#pragma unroll
            for (int r = 0; r < 4; ++r) {
                int m = row0 + mr0 + mi * 16 + quad * 4 + r;
                int bb = m >> 11, ii = m & 2047;
                Obuf[((size_t)(bb * 8 + hh) * N_ + ii) * 64 + dd] = f2bf(acc[mi][ni][r] * scale);
            }
        }
}

// ---------------------------------------------------------------------------
// 5) MFMA flash attention, j-split z=3. Coalesced LDS staging for K/pos/V
//    (round-3 style); lean compute (no online max; ring rel-GEMM; Q in regs).
//    LDS: Ks+Ps+Vt+Pp (72-stride) + Rb ring = 52.5 KB -> 3 blocks/CU.
// ---------------------------------------------------------------------------
#define SLD 72    // bf16 tile row stride (144B: 16B-aligned, conflict-benign)
#define RST 66    // Rb [col][m] stride (132B: 8B-aligned, bank-spread)

__device__ __forceinline__ void stage64(const unsigned short* __restrict__ g,
                                        unsigned short* __restrict__ s, int tid) {
    // 64x64 bf16 tile, global row stride 64 -> LDS row stride SLD
    int r = tid >> 2, d0 = (tid & 3) * 16;
    const uint4* p = reinterpret_cast<const uint4*>(g + (size_t)r * 64 + d0);
    *reinterpret_cast<uint4*>(&s[r * SLD + d0])     = p[0];
    *reinterpret_cast<uint4*>(&s[r * SLD + d0 + 8]) = p[1];
}

__global__ __launch_bounds__(256) void attn_kernel(const unsigned int* __restrict__ flags,
                                                   const unsigned short* __restrict__ qb,
                                                   const unsigned short* __restrict__ kb,
                                                   const unsigned short* __restrict__ vb,
                                                   const unsigned short* __restrict__ posb,
                                                   const void* __restrict__ rcb,
                                                   const void* __restrict__ rpb,
                                                   unsigned short* __restrict__ Opart,
                                                   float* __restrict__ lpart) {
    __shared__ __align__(16) unsigned short Ks[64 * SLD];    // [j][d]
    __shared__ __align__(16) unsigned short Ps[64 * SLD];    // [t][d]
    __shared__ __align__(16) unsigned short Vt[64 * SLD];    // [d][j]
    __shared__ __align__(16) unsigned short Pp[64 * SLD];    // [i][j] (wave-private rows)
    __shared__ __align__(8)  unsigned short Rb[128 * RST];   // rel ring [tcol][m] (wave-private m)

    const int f32 = (int)flags[0];
    const int tid = threadIdx.x;
    const int it = blockIdx.x, bh = blockIdx.y, z = blockIdx.z;
    const int h = bh & 7;
    const int i0 = it * 64;
    const size_t qoff = (size_t)bh * N_ * 64;
    const size_t poff = (size_t)h * 4096 * 64;
    const int lane = tid & 63, w = tid >> 6;
    const int l15 = lane & 15, quad = lane >> 4, q8 = quad * 8;
    const int m0 = w * 16 + quad * 4;

    // ---- Q fragments (contiguous 16B in global, once per block), biases folded ----
    short8 afc[2], afr[2];
#pragma unroll
    for (int kc = 0; kc < 2; ++kc) {
        uint4 qv = *reinterpret_cast<const uint4*>(
            &qb[qoff + (size_t)(i0 + w * 16 + l15) * 64 + kc * 32 + q8]);
        unsigned int uu[4] = {qv.x, qv.y, qv.z, qv.w};
        unsigned int cw[4], rw[4];
#pragma unroll
        for (int e = 0; e < 4; ++e) {
            int k = h * 64 + kc * 32 + q8 + 2 * e;
            float lo = __uint_as_float(uu[e] << 16);
            float hi = __uint_as_float(uu[e] & 0xffff0000u);
            cw[e] = pack2bf(lo + ldf(rcb, f32, k), hi + ldf(rcb, f32, k + 1));
            rw[e] = pack2bf(lo + ldf(rpb, f32, k), hi + ldf(rpb, f32, k + 1));
        }
        union { uint4 u; short8 s; } cv, rv2;
        cv.u  = (uint4){cw[0], cw[1], cw[2], cw[3]};
        rv2.u = (uint4){rw[0], rw[1], rw[2], rw[3]};
        afc[kc] = cv.s;
        afr[kc] = rv2.s;
    }

    float4v Oa[4];
#pragma unroll
    for (int nb = 0; nb < 4; ++nb) Oa[nb] = (float4v){0.f, 0.f, 0.f, 0.f};
    float lsum[4] = {0.f, 0.f, 0.f, 0.f};

    const int base0 = 1984 - i0;
    const int t0 = z * 11, t1 = (z == 2) ? 32 : (t0 + 11);

    // ---- seed ring: stage pos chunk cs0 = base0+t0*64, rel-GEMM -> ring ----
    {
        const int cs0 = base0 + t0 * 64;
        stage64(&posb[poff + (size_t)cs0 * 64], Ps, tid);
        __syncthreads();
        float4v R[4];
#pragma unroll
        for (int nb = 0; nb < 4; ++nb) R[nb] = (float4v){0.f, 0.f, 0.f, 0.f};
#pragma unroll
        for (int kc = 0; kc < 2; ++kc)
#pragma unroll
            for (int nb = 0; nb < 4; ++nb) {
                short8 pb = *reinterpret_cast<const short8*>(&Ps[(nb * 16 + l15) * SLD + kc * 32 + q8]);
                R[nb] = __builtin_amdgcn_mfma_f32_16x16x32_bf16(afr[kc], pb, R[nb], 0, 0, 0);
            }
        const int cb0 = cs0 & 127;
#pragma unroll
        for (int nb = 0; nb < 4; ++nb) {
            union { unsigned short us[4]; uint2 u2; } rv;
#pragma unroll
            for (int r = 0; r < 4; ++r) rv.us[r] = f2bf(R[nb][r]);
            *reinterpret_cast<uint2*>(&Rb[(size_t)(cb0 + nb * 16 + l15) * RST + m0]) = rv.u2;
        }
    }

    for (int jt = t0; jt < t1; ++jt) {
        const int j0 = jt * 64, basej = base0 + j0;
        __syncthreads();   // all waves done reading Ks/Ps/Vt of previous segment

        // ---- coalesced staging: K tile, pos chunk (basej+64), V transposed ----
        stage64(&kb[qoff + (size_t)j0 * 64], Ks, tid);
        stage64(&posb[poff + (size_t)(basej + 64) * 64], Ps, tid);
        {
            int jj = (tid & 31) * 2, dv = (tid >> 5) * 8;
            uint4 r0 = *reinterpret_cast<const uint4*>(&vb[qoff + (size_t)(j0 + jj) * 64 + dv]);
            uint4 r1 = *reinterpret_cast<const uint4*>(&vb[qoff + (size_t)(j0 + jj + 1) * 64 + dv]);
            const unsigned short* p0 = (const unsigned short*)&r0;
            const unsigned short* p1 = (const unsigned short*)&r1;
#pragma unroll
            for (int e = 0; e < 8; ++e) {
                unsigned int pk = (unsigned int)p0[e] | ((unsigned int)p1[e] << 16);
                *reinterpret_cast<unsigned int*>(&Vt[(dv + e) * SLD + jj]) = pk;
            }
        }
        __syncthreads();

        // ---- rel GEMM from Ps -> 64 new ring cols at basej+64 ----
        {
            float4v R[4];
#pragma unroll
            for (int nb = 0; nb < 4; ++nb) R[nb] = (float4v){0.f, 0.f, 0.f, 0.f};
#pragma unroll
            for (int kc = 0; kc < 2; ++kc)
#pragma unroll
                for (int nb = 0; nb < 4; ++nb) {
                    short8 pb = *reinterpret_cast<const short8*>(&Ps[(nb * 16 + l15) * SLD + kc * 32 + q8]);
                    R[nb] = __builtin_amdgcn_mfma_f32_16x16x32_bf16(afr[kc], pb, R[nb], 0, 0, 0);
                }
            const int cb0 = (basej + 64) & 127;
#pragma unroll
            for (int nb = 0; nb < 4; ++nb) {
                union { unsigned short us[4]; uint2 u2; } rv;
#pragma unroll
                for (int r = 0; r < 4; ++r) rv.us[r] = f2bf(R[nb][r]);
                *reinterpret_cast<uint2*>(&Rb[(size_t)(cb0 + nb * 16 + l15) * RST + m0]) = rv.u2;
            }
        }

        // ---- content GEMM: Sacc = Qc · K^T (frags from LDS) ----
        float4v Sacc[4];
#pragma unroll
        for (int nb = 0; nb < 4; ++nb) Sacc[nb] = (float4v){0.f, 0.f, 0.f, 0.f};
#pragma unroll
        for (int kc = 0; kc < 2; ++kc)
#pragma unroll
            for (int nb = 0; nb < 4; ++nb) {
                short8 kf = *reinterpret_cast<const short8*>(&Ks[(nb * 16 + l15) * SLD + kc * 32 + q8]);
                Sacc[nb] = __builtin_amdgcn_mfma_f32_16x16x32_bf16(afc[kc], kf, Sacc[nb], 0, 0, 0);
            }

        // ---- gather rel diagonal, P = exp(S), lane row-sums, stash P ----
#pragma unroll
        for (int nb = 0; nb < 4; ++nb) {
            const int jl = nb * 16 + l15;
#pragma unroll
            for (int r = 0; r < 4; ++r) {
                int t = basej + 63 + jl - (m0 + r);
                float s = Sacc[nb][r] + bf2f(Rb[(size_t)(t & 127) * RST + m0 + r]);
                float p = __expf(s);
                lsum[r] += p;
                Pp[(m0 + r) * SLD + jl] = f2bf(p);
            }
        }

        // ---- PV GEMM: Oa += P · V (Pp rows wave-private; Vt staged pre-barrier) ----
#pragma unroll
        for (int kc = 0; kc < 2; ++kc) {
            short8 pf = *reinterpret_cast<const short8*>(&Pp[(w * 16 + l15) * SLD + kc * 32 + q8]);
#pragma unroll
            for (int nb = 0; nb < 4; ++nb) {
                short8 vf = *reinterpret_cast<const short8*>(&Vt[(nb * 16 + l15) * SLD + kc * 32 + q8]);
                Oa[nb] = __builtin_amdgcn_mfma_f32_16x16x32_bf16(pf, vf, Oa[nb], 0, 0, 0);
            }
        }
    }

    // ---- reduce row sums, write partials ----
#pragma unroll
    for (int r = 0; r < 4; ++r)
#pragma unroll
        for (int off = 1; off < 16; off <<= 1) lsum[r] += __shfl_xor(lsum[r], off);
    const size_t pslot = (size_t)(z * 16 + bh) * 32 + it;
    const size_t obase = pslot * 4096;
#pragma unroll
    for (int nb = 0; nb < 4; ++nb)
#pragma unroll
        for (int r = 0; r < 4; ++r)
            Opart[obase + (size_t)(m0 + r) * 64 + nb * 16 + l15] = f2bf(Oa[nb][r]);
    if (l15 == 0) {
#pragma unroll
        for (int r = 0; r < 4; ++r) lpart[pslot * 64 + m0 + r] = lsum[r];
    }
}

// ---------------------------------------------------------------------------
// 6) Combine j-split partials, normalize, write ao[b][i][h*64+d] bf16.
// ---------------------------------------------------------------------------
__global__ __launch_bounds__(256) void combine_kernel(const unsigned short* __restrict__ Opart,
                                                      const float* __restrict__ lpart,
                                                      unsigned short* __restrict__ ao) {
    const int it = blockIdx.x, bh = blockIdx.y;
    const int h = bh & 7, b = bh >> 3, i0 = it * 64;
    const int tid = threadIdx.x;
    const int row = tid >> 2, c0 = (tid & 3) * 16;
    float o[16];
#pragma unroll
    for (int e = 0; e < 16; ++e) o[e] = 0.f;
    float l = 0.f;
#pragma unroll
    for (int z = 0; z < 3; ++z) {
        const size_t pslot = (size_t)(z * 16 + bh) * 32 + it;
        const size_t ob = pslot * 4096 + (size_t)row * 64 + c0;
        uint4 a = *reinterpret_cast<const uint4*>(&Opart[ob]);
        uint4 b4 = *reinterpret_cast<const uint4*>(&Opart[ob + 8]);
        unsigned int uu[8] = {a.x, a.y, a.z, a.w, b4.x, b4.y, b4.z, b4.w};
#pragma unroll
        for (int e = 0; e < 8; ++e) {
            o[2 * e]     += __uint_as_float(uu[e] << 16);
            o[2 * e + 1] += __uint_as_float(uu[e] & 0xffff0000u);
        }
        l += lpart[pslot * 64 + row];
    }
    float inv = 1.0f / l;
    unsigned int ou[8];
#pragma unroll
    for (int e = 0; e < 8; ++e) ou[e] = pack2bf(o[2 * e] * inv, o[2 * e + 1] * inv);
    unsigned short* dst = &ao[((size_t)b * N_ + i0 + row) * 512 + h * 64 + c0];
    *reinterpret_cast<uint4*>(dst)     = (uint4){ou[0], ou[1], ou[2], ou[3]};
    *reinterpret_cast<uint4*>(dst + 8) = (uint4){ou[4], ou[5], ou[6], ou[7]};
}

// ---------------------------------------------------------------------------
// 7) out = ao @ Wo + bo (output dtype per flag). grid (12, 64).
// ---------------------------------------------------------------------------
__global__ __launch_bounds__(256) void outproj_kernel(const unsigned int* __restrict__ flags,
                                                      const unsigned short* __restrict__ AO,
                                                      const unsigned short* __restrict__ Wot,
                                                      const void* __restrict__ bo,
                                                      void* __restrict__ out) {
    __shared__ __align__(16) unsigned short As[64 * 32];
    __shared__ __align__(16) unsigned short Bs[128 * 32];
    const int f32 = (int)flags[0];
    const int row0 = blockIdx.y * 64, col0 = blockIdx.x * 128;
    float4v acc[2][4];
#pragma unroll
    for (int mi = 0; mi < 2; ++mi)
#pragma unroll
        for (int ni = 0; ni < 4; ++ni) acc[mi][ni] = (float4v){0.f, 0.f, 0.f, 0.f};
    gemm64x128_core(AO, Wot, 512, row0, col0, As, Bs, acc);
    const int lane = threadIdx.x & 63, w = threadIdx.x >> 6;
    const int l15 = lane & 15, quad = lane >> 4;
    const int mr0 = (w & 1) * 32, nc0 = (w >> 1) * 64;
#pragma unroll
    for (int mi = 0; mi < 2; ++mi)
#pragma unroll
        for (int ni = 0; ni < 4; ++ni) {
            int n = col0 + nc0 + ni * 16 + l15;
            float bias = ldf(bo, f32, n);
#pragma unroll
            for (int r = 0; r < 4; ++r) {
                int m = row0 + mr0 + mi * 16 + quad * 4 + r;
                float v = acc[mi][ni][r] + bias;
                if (f32) ((float*)out)[(size_t)m * DIM_ + n] = v;
                else     ((unsigned short*)out)[(size_t)m * DIM_ + n] = f2bf(v);
            }
        }
}

// ---------------------------------------------------------------------------
extern "C" void kernel_launch(void* const* d_in, const int* in_sizes, int n_in,
                              void* d_out, int out_size, void* d_ws, size_t ws_size,
                              hipStream_t stream) {
    const void* x    = d_in[0];
    const void* Wq   = d_in[1];
    const void* Wk   = d_in[2];
    const void* Wv   = d_in[3];
    const void* Wo   = d_in[4];
    const void* bo   = d_in[5];
    const void* Wrel = d_in[6];
    const void* rcb  = d_in[7];
    const void* rpb  = d_in[8];

    char* ws = (char*)d_ws;
    unsigned int*   flags = (unsigned int*)(ws + OFF_FLAG);
    unsigned short* posb  = (unsigned short*)(ws + OFF_POS);
    unsigned short* qbuf  = (unsigned short*)(ws + OFF_Q);
    unsigned short* kbuf  = (unsigned short*)(ws + OFF_K);
    unsigned short* vbuf  = (unsigned short*)(ws + OFF_V);
    unsigned short* Wot   = (unsigned short*)(ws + OFF_WOT);
    unsigned short* Xb    = (unsigned short*)(ws + OFF_XB);
    unsigned short* ao    = (unsigned short*)(ws + OFF_AO);
    unsigned short* Opart = (unsigned short*)(ws + OFF_OP);
    float*          lpart = (float*)(ws + OFF_LP);
    unsigned short* Wt    = (unsigned short*)(ws + OFF_WT);

    // maxp: pure function of compile-time constants; host-side (capture-time only)
    double maxp = 0.0;
    for (int g = 0; g < NB_; ++g) {
        double mean = 64.0 * (g + 1);
        double conc = (mean / 32.0) * (mean / 32.0);
        double rate = mean / 1024.0;
        double lgc  = std::lgamma(conc);
        double clr  = conc * std::log(rate);
        for (int ad = 1; ad < N_; ++ad) {
            double lp = (conc - 1.0) * std::log((double)ad) - rate * (double)ad - lgc + clr;
            double p  = std::exp(lp) + 1e-8;
            if (p > maxp) maxp = p;
        }
    }

    detect_kernel<<<dim3(1), dim3(256), 0, stream>>>((const unsigned short*)x, flags);
    cvtx_kernel<<<dim3(1024), dim3(256), 0, stream>>>(flags, x, Xb);
    cvtw_kernel<<<dim3(16, 48, 4), dim3(256), 0, stream>>>(flags, Wq, Wk, Wv, Wo, Wt, Wot);
    posproj_kernel<<<dim3(512), dim3(512), 0, stream>>>(maxp, Wrel, flags, posb);
    qkv_kernel<<<dim3(12, 64), dim3(256), 0, stream>>>(Xb, Wt, qbuf, kbuf, vbuf);
    attn_kernel<<<dim3(32, 16, 3), dim3(256), 0, stream>>>(flags, qbuf, kbuf, vbuf, posb, rcb, rpb, Opart, lpart);
    combine_kernel<<<dim3(32, 16), dim3(256), 0, stream>>>(Opart, lpart, ao);
    outproj_kernel<<<dim3(12, 64), dim3(256), 0, stream>>>(flags, ao, Wot, bo, d_out);
}